// Round 3
// baseline (665.182 us; speedup 1.0000x reference)
//
#include <hip/hip_runtime.h>
#include <hip/hip_bf16.h>
#include <cstdint>

// ---------------------------------------------------------------------------
// LinearAttention on MI355X (gfx950)
// L=4096, N=4, E=1024, H=16, D=64.  M = L*N = 16384.
// Round 3: software-pipelined double-buffered GEMM K-loop. All global traffic
// for tile k+1 (A-fp32 register prefetch + B global_load_lds) issues BEFORE
// the MFMAs of tile k, so the barrier drain at the end of the iteration only
// pays residual latency. Keeps round-2's LDS-staged packed epilogue
// (WRITE_SIZE 65.7->32.8 MB confirmed) and fused fp32->bf16 A conversion.
// ---------------------------------------------------------------------------

typedef __attribute__((ext_vector_type(8))) short bf16x8;
typedef __attribute__((ext_vector_type(4))) float f32x4;

#define L_SEQ 4096
#define NBATCH 4
#define EMB 1024
#define NHEADS 16
#define HDIM 64
#define MROWS (L_SEQ * NBATCH)   // 16384
#define NHG (NBATCH * NHEADS)    // 64 head-groups
#define LCHUNK 512
#define NCHUNK (L_SEQ / LCHUNK)  // 8

__device__ __forceinline__ unsigned short f2bf(float f) {
  union { float f; uint32_t u; } v; v.f = f;
  uint32_t u = v.u;
  u += 0x7fffu + ((u >> 16) & 1u);   // round-to-nearest-even
  return (unsigned short)(u >> 16);
}
__device__ __forceinline__ float bf2f(unsigned short s) {
  union { uint32_t u; float f; } v; v.u = ((uint32_t)s) << 16;
  return v.f;
}
// pack two fp32 -> two bf16 (round-half-up; 0.5-ULP bound, ~3 VALU)
__device__ __forceinline__ uint32_t pkbf(float a, float b) {
  union { float f; uint32_t u; } ua, ub; ua.f = a; ub.f = b;
  return ((ua.u + 0x8000u) >> 16) | ((ub.u + 0x8000u) & 0xffff0000u);
}

// ---------------- fp32 -> bf16 convert, 4 weight matrices in one dispatch ---
__global__ __launch_bounds__(256) void convert_w4(const float* __restrict__ s0,
                                                  const float* __restrict__ s1,
                                                  const float* __restrict__ s2,
                                                  const float* __restrict__ s3,
                                                  unsigned short* __restrict__ d0,
                                                  unsigned short* __restrict__ d1,
                                                  unsigned short* __restrict__ d2,
                                                  unsigned short* __restrict__ d3,
                                                  int n) {
  const int w = blockIdx.y;
  const float* src = (w == 0) ? s0 : (w == 1) ? s1 : (w == 2) ? s2 : s3;
  unsigned short* dst = (w == 0) ? d0 : (w == 1) ? d1 : (w == 2) ? d2 : d3;
  int i = (blockIdx.x * 256 + threadIdx.x) * 4;
  if (i + 4 <= n) {
    float4 f = *(const float4*)(src + i);
    uint2 p;
    p.x = pkbf(f.x, f.y);
    p.y = pkbf(f.z, f.w);
    *(uint2*)(dst + i) = p;
  }
}

// ---------------- bf16 MFMA GEMM: C = A(MxK) . B(NnxK)^T + bias -------------
// MODE 0: elu(x)+1 -> bf16 ; MODE 1: x -> bf16 ; MODE 2: x -> fp32
// AF32: A is fp32 in global, converted to bf16 during (pipelined) LDS staging.
// M % 128 == 0, Nn % 128 == 0, K % 32 == 0. Block 256 (4 waves), tile 128x128.
// LDS: double-buffered 128x32 bf16 tiles for A and B (4 x 8 KB).
template <int MODE, bool AF32>
__global__ __launch_bounds__(256) void gemm_bt(const void* __restrict__ Av,
                                               const unsigned short* __restrict__ B,
                                               const float* __restrict__ bias,
                                               void* __restrict__ Cout,
                                               int M, int Nn, int K) {
  __shared__ __align__(16) char smem[32768];
  // As buf b at smem + b*8192 ; Bs buf b at smem + 16384 + b*8192

  const int tid  = threadIdx.x;
  const int wave = tid >> 6;
  const int lane = tid & 63;
  const int col  = lane & 15;    // n (B-frag) / m (A-frag) lane index
  const int quad = lane >> 4;    // k-group for frags, row-group for C
  const int m0 = (wave >> 1) * 64;
  const int n0 = (wave & 1) * 64;
  const long arow0 = (long)blockIdx.x * 128;
  const long brow0 = (long)blockIdx.y * 128;

  const f32x4 fzero = {0.f, 0.f, 0.f, 0.f};
  f32x4 acc[4][4];
#pragma unroll
  for (int i = 0; i < 4; i++)
#pragma unroll
    for (int j = 0; j < 4; j++) acc[i][j] = fzero;

  // global_load_lds staging: 8 segments of 1 KB; wave handles segs w*2, w*2+1
  const int seg0  = wave * 2;
  const int srow  = lane >> 2;
  const int skoff = (lane & 3) * 8;
  // fp32-A staging: 4 phases x (256 thr x 4 fp32); phase r covers rows r*32..+31
  const int frow = tid >> 3;       // row within phase block (0..31)
  const int fcol = (tid & 7) * 4;  // fp32 col within K-tile (== short offset)

  const float* Af = (const float*)Av;
  const unsigned short* Ab = (const unsigned short*)Av;

  float4 pre[4];

  // ---- prologue: stage tile kt=0 into buffer 0 ----
  if (AF32) {
#pragma unroll
    for (int r = 0; r < 4; r++)
      pre[r] = *(const float4*)(Af + (arow0 + r * 32 + frow) * (long)K + fcol);
#pragma unroll
    for (int r = 0; r < 2; r++) {
      const int seg = seg0 + r;
      const int row = seg * 16 + srow;
      __builtin_amdgcn_global_load_lds(
          (const __attribute__((address_space(1))) void*)(B + (brow0 + row) * (long)K + skoff),
          (__attribute__((address_space(3))) void*)(smem + 16384 + seg * 1024 + (lane & 3) * 16),
          16, 0, 0);
    }
    unsigned short* Ad = (unsigned short*)smem;
#pragma unroll
    for (int r = 0; r < 4; r++) {
      uint2 p;
      p.x = pkbf(pre[r].x, pre[r].y);
      p.y = pkbf(pre[r].z, pre[r].w);
      *(uint2*)(&Ad[(r * 32 + frow) * 32 + fcol]) = p;
    }
  } else {
#pragma unroll
    for (int r = 0; r < 2; r++) {
      const int seg = seg0 + r;
      const int row = seg * 16 + srow;
      __builtin_amdgcn_global_load_lds(
          (const __attribute__((address_space(1))) void*)(Ab + (arow0 + row) * (long)K + skoff),
          (__attribute__((address_space(3))) void*)(smem + seg * 1024 + (lane & 3) * 16),
          16, 0, 0);
      __builtin_amdgcn_global_load_lds(
          (const __attribute__((address_space(1))) void*)(B + (brow0 + row) * (long)K + skoff),
          (__attribute__((address_space(3))) void*)(smem + 16384 + seg * 1024 + (lane & 3) * 16),
          16, 0, 0);
    }
  }
  __syncthreads();

  // ---- pipelined K-loop ----
  int buf = 0;
  for (int kt = 32;; kt += 32) {
    const bool more = (kt < K);

    // stage tile kt into buf^1 (issues only; latency covered by MFMAs below)
    if (more) {
      if (AF32) {
#pragma unroll
        for (int r = 0; r < 4; r++)
          pre[r] = *(const float4*)(Af + (arow0 + r * 32 + frow) * (long)K + kt + fcol);
#pragma unroll
        for (int r = 0; r < 2; r++) {
          const int seg = seg0 + r;
          const int row = seg * 16 + srow;
          __builtin_amdgcn_global_load_lds(
              (const __attribute__((address_space(1))) void*)(B + (brow0 + row) * (long)K + kt + skoff),
              (__attribute__((address_space(3))) void*)(smem + 16384 + (buf ^ 1) * 8192 + seg * 1024 + (lane & 3) * 16),
              16, 0, 0);
        }
      } else {
#pragma unroll
        for (int r = 0; r < 2; r++) {
          const int seg = seg0 + r;
          const int row = seg * 16 + srow;
          __builtin_amdgcn_global_load_lds(
              (const __attribute__((address_space(1))) void*)(Ab + (arow0 + row) * (long)K + kt + skoff),
              (__attribute__((address_space(3))) void*)(smem + (buf ^ 1) * 8192 + seg * 1024 + (lane & 3) * 16),
              16, 0, 0);
          __builtin_amdgcn_global_load_lds(
              (const __attribute__((address_space(1))) void*)(B + (brow0 + row) * (long)K + kt + skoff),
              (__attribute__((address_space(3))) void*)(smem + 16384 + (buf ^ 1) * 8192 + seg * 1024 + (lane & 3) * 16),
              16, 0, 0);
        }
      }
    }

    // compute on buf
    const unsigned short* Asb = (const unsigned short*)(smem + buf * 8192);
    const unsigned short* Bsb = (const unsigned short*)(smem + 16384 + buf * 8192);
    bf16x8 af[4], bfr[4];
#pragma unroll
    for (int i = 0; i < 4; i++) {
      af[i]  = *(const bf16x8*)(&Asb[(m0 + i * 16 + col) * 32 + quad * 8]);
      bfr[i] = *(const bf16x8*)(&Bsb[(n0 + i * 16 + col) * 32 + quad * 8]);
    }
#pragma unroll
    for (int i = 0; i < 4; i++)
#pragma unroll
      for (int j = 0; j < 4; j++)
        acc[i][j] = __builtin_amdgcn_mfma_f32_16x16x32_bf16(af[i], bfr[j], acc[i][j], 0, 0, 0);

    // pack prefetched A regs into As[buf^1] (waits only on own A loads)
    if (more && AF32) {
      unsigned short* Ad = (unsigned short*)(smem + (buf ^ 1) * 8192);
#pragma unroll
      for (int r = 0; r < 4; r++) {
        uint2 p;
        p.x = pkbf(pre[r].x, pre[r].y);
        p.y = pkbf(pre[r].z, pre[r].w);
        *(uint2*)(&Ad[(r * 32 + frow) * 32 + fcol]) = p;
      }
    }
    __syncthreads();
    if (!more) break;
    buf ^= 1;
  }

  // ---- epilogue: stage 32rows x 128cols slabs through LDS, packed stores ---
  // C/D frag layout: col = lane&15, row = quad*4 + reg.
  float bcol[4];
#pragma unroll
  for (int j = 0; j < 4; j++) bcol[j] = bias[brow0 + n0 + j * 16 + col];

  const int wp   = wave >> 1;   // wave-pair: rows m-base = wp*64
  const int lrow = tid >> 3;    // readback row 0..31
  const int cch  = tid & 7;     // readback col-chunk (16 elems each)

  if (MODE != 2) {
    unsigned short* epi = (unsigned short*)smem;
    const int EST = 136;  // shorts; 272 B row stride (16B-aligned, bank-skewed)
#pragma unroll
    for (int i = 0; i < 4; i++) {
#pragma unroll
      for (int j = 0; j < 4; j++) {
#pragma unroll
        for (int rr = 0; rr < 4; rr++) {
          float vv = acc[i][j][rr] + bcol[j];
          if (MODE == 0) vv = (vv > 0.f) ? (vv + 1.f) : __expf(vv);  // elu+1
          epi[(wp * 16 + quad * 4 + rr) * EST + n0 + j * 16 + col] = f2bf(vv);
        }
      }
      __syncthreads();
      const long gr = arow0 + (long)(lrow >> 4) * 64 + i * 16 + (lrow & 15);
      const long gc = brow0 + cch * 16;
      const unsigned short* src = &epi[lrow * EST + cch * 16];
      uint4 a  = *(const uint4*)src;
      uint4 b2 = *(const uint4*)(src + 8);
      unsigned short* Cp = (unsigned short*)Cout + gr * Nn + gc;
      *(uint4*)Cp       = a;
      *(uint4*)(Cp + 8) = b2;
      __syncthreads();
    }
  } else {
    float* epi = (float*)smem;
    const int ESF = 132;  // floats; 528 B row stride (16B-aligned, bank-skewed)
#pragma unroll
    for (int i = 0; i < 4; i++) {
#pragma unroll
      for (int j = 0; j < 4; j++) {
#pragma unroll
        for (int rr = 0; rr < 4; rr++) {
          epi[(wp * 16 + quad * 4 + rr) * ESF + n0 + j * 16 + col] =
              acc[i][j][rr] + bcol[j];
        }
      }
      __syncthreads();
      const long gr = arow0 + (long)(lrow >> 4) * 64 + i * 16 + (lrow & 15);
      const long gc = brow0 + cch * 16;
      const float* src = &epi[lrow * ESF + cch * 16];
      float* Cp = (float*)Cout + gr * Nn + gc;
#pragma unroll
      for (int s = 0; s < 4; s++)
        *(float4*)(Cp + s * 4) = *(const float4*)(src + s * 4);
      __syncthreads();
    }
  }
}

// ---------------- kv partials: kv[d][e] = sum_l kf[l][d]*v[l][e] ------------
// grid (NHG, NCHUNK), block 256. Non-atomic partial outputs per chunk.
__global__ __launch_bounds__(256) void kv_partial_kernel(const unsigned short* __restrict__ kf,
                                                         const unsigned short* __restrict__ vp,
                                                         float* __restrict__ kvp,
                                                         float* __restrict__ ksp) {
  __shared__ float ks[32 * 64];
  __shared__ float vs[32 * 64];
  const int hg = blockIdx.x;
  const int chunk = blockIdx.y;
  const int n = hg >> 4, h = hg & 15;
  const int tid = threadIdx.x;
  const int td = tid >> 4, te = tid & 15;   // thread covers d=td*4..+3, e=te*4..+3
  const long hoff = (long)n * EMB + h * HDIM;
  const int l0 = chunk * LCHUNK;

  float acc[4][4];
#pragma unroll
  for (int i = 0; i < 4; i++)
#pragma unroll
    for (int j = 0; j < 4; j++) acc[i][j] = 0.f;
  float ksacc[4] = {0.f, 0.f, 0.f, 0.f};

  const int lrow = tid >> 3;         // 0..31
  const int dcol = (tid & 7) * 8;    // 0..56

  for (int ls = 0; ls < LCHUNK; ls += 32) {
    const long g = (long)(l0 + ls + lrow) * (NBATCH * EMB) + hoff + dcol;
    uint4 kr = *(const uint4*)(kf + g);
    uint4 vr = *(const uint4*)(vp + g);
    float* kd = &ks[lrow * 64 + dcol];
    float* vd = &vs[lrow * 64 + dcol];
    uint32_t ku[4] = {kr.x, kr.y, kr.z, kr.w};
    uint32_t vu[4] = {vr.x, vr.y, vr.z, vr.w};
#pragma unroll
    for (int t2 = 0; t2 < 4; t2++) {
      kd[2 * t2]     = bf2f((unsigned short)(ku[t2] & 0xffffu));
      kd[2 * t2 + 1] = bf2f((unsigned short)(ku[t2] >> 16));
      vd[2 * t2]     = bf2f((unsigned short)(vu[t2] & 0xffffu));
      vd[2 * t2 + 1] = bf2f((unsigned short)(vu[t2] >> 16));
    }
    __syncthreads();
#pragma unroll
    for (int l = 0; l < 32; l++) {
      float kq[4], vq[4];
      *(float4*)kq = *(const float4*)(&ks[l * 64 + td * 4]);
      *(float4*)vq = *(const float4*)(&vs[l * 64 + te * 4]);
#pragma unroll
      for (int i = 0; i < 4; i++) {
        ksacc[i] += kq[i];
#pragma unroll
        for (int j = 0; j < 4; j++) acc[i][j] += kq[i] * vq[j];
      }
    }
    __syncthreads();
  }
  float* outp = kvp + ((long)chunk * NHG + hg) * 4096;
#pragma unroll
  for (int i = 0; i < 4; i++)
#pragma unroll
    for (int j = 0; j < 4; j++)
      outp[(td * 4 + i) * 64 + te * 4 + j] = acc[i][j];
  if (te == 0) {
    float* o2 = ksp + ((long)chunk * NHG + hg) * 64;
#pragma unroll
    for (int i = 0; i < 4; i++) o2[td * 4 + i] = ksacc[i];
  }
}

// ---------------- out1 = (qf @ kv) * 1/(qf.ksum + eps), bf16 row-major ------
// grid (NHG, 16), block 256. Each block: one head, 256 l-values (4 x 64).
__global__ __launch_bounds__(256) void attn_out_kernel(const unsigned short* __restrict__ qf,
                                                       const float* __restrict__ kvp,
                                                       const float* __restrict__ ksp,
                                                       unsigned short* __restrict__ out1) {
  __shared__ float kv_s[64 * 64];   // [d][e]
  __shared__ float ksum_s[64];
  __shared__ float qs[64 * 64];     // [d][l] transposed (bank-conflict-free reads)
  const int hg = blockIdx.x;
  const int lc = blockIdx.y;
  const int n = hg >> 4, h = hg & 15;
  const int tid = threadIdx.x;
  const int lane_l = tid & 63;   // l within sub-chunk
  const int eg = tid >> 6;       // wave -> e-group of 16
  const long hoff = (long)n * EMB + h * HDIM;

  // reduce kv partials into LDS
  for (int w = tid; w < 4096; w += 256) {
    float s = 0.f;
#pragma unroll
    for (int c = 0; c < NCHUNK; c++) s += kvp[((long)c * NHG + hg) * 4096 + w];
    kv_s[w] = s;
  }
  if (tid < 64) {
    float s = 0.f;
#pragma unroll
    for (int c = 0; c < NCHUNK; c++) s += ksp[((long)c * NHG + hg) * 64 + tid];
    ksum_s[tid] = s;
  }
  __syncthreads();

  const int sl = tid >> 2;           // staging l (0..63)
  const int sd0 = (tid & 3) * 16;    // staging d start

  for (int sc = 0; sc < 4; sc++) {
    const int lbase = lc * 256 + sc * 64;
    {
      const long g = (long)(lbase + sl) * (NBATCH * EMB) + hoff + sd0;
      uint4 a  = *(const uint4*)(qf + g);
      uint4 b2 = *(const uint4*)(qf + g + 8);
      uint32_t u[8] = {a.x, a.y, a.z, a.w, b2.x, b2.y, b2.z, b2.w};
#pragma unroll
      for (int t2 = 0; t2 < 8; t2++) {
        qs[(sd0 + 2 * t2) * 64 + sl]     = bf2f((unsigned short)(u[t2] & 0xffffu));
        qs[(sd0 + 2 * t2 + 1) * 64 + sl] = bf2f((unsigned short)(u[t2] >> 16));
      }
    }
    __syncthreads();

    float accv[16];
#pragma unroll
    for (int j = 0; j < 16; j++) accv[j] = 0.f;
    float denom = 0.f;
#pragma unroll 8
    for (int d = 0; d < 64; d++) {
      const float qd = qs[d * 64 + lane_l];
      denom += qd * ksum_s[d];
      const float* kvrow = &kv_s[d * 64 + eg * 16];
      float kvv[16];
      *(float4*)(kvv)      = *(const float4*)(kvrow);
      *(float4*)(kvv + 4)  = *(const float4*)(kvrow + 4);
      *(float4*)(kvv + 8)  = *(const float4*)(kvrow + 8);
      *(float4*)(kvv + 12) = *(const float4*)(kvrow + 12);
#pragma unroll
      for (int j = 0; j < 16; j++) accv[j] += qd * kvv[j];
    }
    const float z = 1.f / (denom + 1e-6f);
    const long ro = ((long)(lbase + lane_l) * NBATCH + n) * EMB + h * HDIM + eg * 16;
    uint32_t pk[8];
#pragma unroll
    for (int j = 0; j < 8; j++) {
      unsigned short lo = f2bf(accv[2 * j] * z);
      unsigned short hi = f2bf(accv[2 * j + 1] * z);
      pk[j] = (uint32_t)lo | ((uint32_t)hi << 16);
    }
    *(uint4*)(out1 + ro)     = make_uint4(pk[0], pk[1], pk[2], pk[3]);
    *(uint4*)(out1 + ro + 8) = make_uint4(pk[4], pk[5], pk[6], pk[7]);
    __syncthreads();
  }
}

// ---------------------------------------------------------------------------
extern "C" void kernel_launch(void* const* d_in, const int* in_sizes, int n_in,
                              void* d_out, int out_size, void* d_ws, size_t ws_size,
                              hipStream_t stream) {
  const float* q  = (const float*)d_in[0];
  const float* k  = (const float*)d_in[1];
  const float* v  = (const float*)d_in[2];
  const float* Wq = (const float*)d_in[3];
  const float* bq = (const float*)d_in[4];
  const float* Wk = (const float*)d_in[5];
  const float* bk = (const float*)d_in[6];
  const float* Wv = (const float*)d_in[7];
  const float* bv = (const float*)d_in[8];
  const float* Wo = (const float*)d_in[9];
  const float* bo = (const float*)d_in[10];

  char* ws = (char*)d_ws;
  const size_t BUF = (size_t)MROWS * EMB * 2;  // 33,554,432 B
  unsigned short* T0  = (unsigned short*)(ws);              // out1 staging
  unsigned short* qf  = (unsigned short*)(ws + BUF);
  unsigned short* kf  = (unsigned short*)(ws + 2 * BUF);
  unsigned short* vp  = (unsigned short*)(ws + 3 * BUF);
  unsigned short* Wqb = (unsigned short*)(ws + 4 * BUF);
  unsigned short* Wkb = Wqb + (size_t)EMB * EMB;
  unsigned short* Wvb = Wkb + (size_t)EMB * EMB;
  unsigned short* Wob = Wvb + (size_t)EMB * EMB;
  float* kvp = (float*)(ws + 4 * BUF + 4 * (size_t)EMB * EMB * 2);
  float* ksp = kvp + (size_t)NCHUNK * NHG * HDIM * HDIM;

  const int nW = EMB * EMB;  // 1,048,576

  // all 4 weight matrices -> bf16 in one dispatch
  convert_w4<<<dim3(nW / 1024, 4), 256, 0, stream>>>(Wq, Wk, Wv, Wo,
                                                     Wqb, Wkb, Wvb, Wob, nW);

  dim3 gg(MROWS / 128, EMB / 128), bb(256);

  // projections with pipelined fused fp32->bf16 A conversion
  gemm_bt<0, true><<<gg, bb, 0, stream>>>(q, Wqb, bq, qf, MROWS, EMB, EMB);
  gemm_bt<0, true><<<gg, bb, 0, stream>>>(k, Wkb, bk, kf, MROWS, EMB, EMB);
  gemm_bt<1, true><<<gg, bb, 0, stream>>>(v, Wvb, bv, vp, MROWS, EMB, EMB);

  // attention state + output (out1 -> T0)
  kv_partial_kernel<<<dim3(NHG, NCHUNK), 256, 0, stream>>>(kf, vp, kvp, ksp);
  attn_out_kernel<<<dim3(NHG, L_SEQ / 256), 256, 0, stream>>>(qf, kvp, ksp, T0);

  // final projection -> fp32 output
  gemm_bt<2, false><<<gg, bb, 0, stream>>>(T0, Wob, bo, d_out, MROWS, EMB, EMB);
}

// Round 4
// 561.484 us; speedup vs baseline: 1.1847x; 1.1847x over previous
//
#include <hip/hip_runtime.h>
#include <hip/hip_bf16.h>
#include <cstdint>

// ---------------------------------------------------------------------------
// LinearAttention on MI355X (gfx950)
// L=4096, N=4, E=1024, H=16, D=64.  M = L*N = 16384.
// Round 4: revert to round-1 single-buffered global_load_lds staging (best
// measured), keep round-2 LDS-staged packed epilogue (WRITE 2x fix confirmed),
// and widen the K-step to BK=64 as TWO BK=32 sub-tiles in separate LDS
// buffers: 8 global_load_lds per thread -> ONE barrier -> 32 MFMAs. Halves
// the vmcnt(0)+s_barrier drain count while keeping the verified conflict-free
// BK=32 LDS layout (padding would break global_load_lds lane contiguity).
// AF32 in-GEMM conversion abandoned (0-for-2: sync chain R2, VALU bloat R3).
// ---------------------------------------------------------------------------

typedef __attribute__((ext_vector_type(8))) short bf16x8;
typedef __attribute__((ext_vector_type(4))) float f32x4;

#define L_SEQ 4096
#define NBATCH 4
#define EMB 1024
#define NHEADS 16
#define HDIM 64
#define MROWS (L_SEQ * NBATCH)   // 16384
#define NHG (NBATCH * NHEADS)    // 64 head-groups
#define LCHUNK 512
#define NCHUNK (L_SEQ / LCHUNK)  // 8

__device__ __forceinline__ unsigned short f2bf(float f) {
  union { float f; uint32_t u; } v; v.f = f;
  uint32_t u = v.u;
  u += 0x7fffu + ((u >> 16) & 1u);   // round-to-nearest-even
  return (unsigned short)(u >> 16);
}
__device__ __forceinline__ float bf2f(unsigned short s) {
  union { uint32_t u; float f; } v; v.u = ((uint32_t)s) << 16;
  return v.f;
}
__device__ __forceinline__ uint32_t pkbf(float a, float b) {
  union { float f; uint32_t u; } ua, ub; ua.f = a; ub.f = b;
  return ((ua.u + 0x8000u) >> 16) | ((ub.u + 0x8000u) & 0xffff0000u);
}

// ---------------- fp32 -> bf16 convert ---------------------------------------
__global__ __launch_bounds__(256) void convert_kernel(const float* __restrict__ src,
                                                      unsigned short* __restrict__ dst,
                                                      int n) {
  int i = (blockIdx.x * 256 + threadIdx.x) * 4;
  if (i + 4 <= n) {
    float4 f = *(const float4*)(src + i);
    uint2 p;
    p.x = pkbf(f.x, f.y);
    p.y = pkbf(f.z, f.w);
    *(uint2*)(dst + i) = p;
  }
}

// ---------------- fp32 -> bf16 convert, 4 weight matrices in one dispatch ---
__global__ __launch_bounds__(256) void convert_w4(const float* __restrict__ s0,
                                                  const float* __restrict__ s1,
                                                  const float* __restrict__ s2,
                                                  const float* __restrict__ s3,
                                                  unsigned short* __restrict__ d0,
                                                  unsigned short* __restrict__ d1,
                                                  unsigned short* __restrict__ d2,
                                                  unsigned short* __restrict__ d3,
                                                  int n) {
  const int w = blockIdx.y;
  const float* src = (w == 0) ? s0 : (w == 1) ? s1 : (w == 2) ? s2 : s3;
  unsigned short* dst = (w == 0) ? d0 : (w == 1) ? d1 : (w == 2) ? d2 : d3;
  int i = (blockIdx.x * 256 + threadIdx.x) * 4;
  if (i + 4 <= n) {
    float4 f = *(const float4*)(src + i);
    uint2 p;
    p.x = pkbf(f.x, f.y);
    p.y = pkbf(f.z, f.w);
    *(uint2*)(dst + i) = p;
  }
}

// ---------------- bf16 MFMA GEMM: C = A(MxK) . B(NnxK)^T + bias -------------
// MODE 0: elu(x)+1 -> bf16 ; MODE 1: x -> bf16 ; MODE 2: x -> fp32
// M % 128 == 0, Nn % 128 == 0, K % 64 == 0. Block 256 (4 waves), tile 128x128.
// K-step 64 = two BK=32 sub-tiles (verified layout), one barrier per 32 MFMAs.
// LDS: As0 @0, As1 @8K, Bs0 @16K, Bs1 @24K (32 KB; 4-5 blocks/CU).
template <int MODE>
__global__ __launch_bounds__(256) void gemm_bt(const unsigned short* __restrict__ A,
                                               const unsigned short* __restrict__ B,
                                               const float* __restrict__ bias,
                                               void* __restrict__ Cout,
                                               int M, int Nn, int K) {
  __shared__ __align__(16) char smem[32768];

  const int tid  = threadIdx.x;
  const int wave = tid >> 6;
  const int lane = tid & 63;
  const int col  = lane & 15;    // n (B-frag) / m (A-frag) lane index
  const int quad = lane >> 4;    // k-group for frags, row-group for C
  const int m0 = (wave >> 1) * 64;
  const int n0 = (wave & 1) * 64;
  const long arow0 = (long)blockIdx.x * 128;
  const long brow0 = (long)blockIdx.y * 128;

  const f32x4 fzero = {0.f, 0.f, 0.f, 0.f};
  f32x4 acc[4][4];
#pragma unroll
  for (int i = 0; i < 4; i++)
#pragma unroll
    for (int j = 0; j < 4; j++) acc[i][j] = fzero;

  // staging: per BK=32 sub-tile, 8 segments of 1 KB; wave w covers segs 2w,2w+1
  // lane -> row = seg*16 + (lane>>2), k-short-off = (lane&3)*8
  const int seg0  = wave * 2;
  const int srow  = lane >> 2;
  const int skoff = (lane & 3) * 8;

  for (int kt = 0; kt < K; kt += 64) {
#pragma unroll
    for (int s = 0; s < 2; s++) {
#pragma unroll
      for (int r = 0; r < 2; r++) {
        const int seg = seg0 + r;
        const int row = seg * 16 + srow;
        const unsigned short* ga = A + (arow0 + row) * (long)K + kt + s * 32 + skoff;
        const unsigned short* gb = B + (brow0 + row) * (long)K + kt + s * 32 + skoff;
        __builtin_amdgcn_global_load_lds(
            (const __attribute__((address_space(1))) void*)ga,
            (__attribute__((address_space(3))) void*)(smem + s * 8192 + seg * 1024),
            16, 0, 0);
        __builtin_amdgcn_global_load_lds(
            (const __attribute__((address_space(1))) void*)gb,
            (__attribute__((address_space(3))) void*)(smem + 16384 + s * 8192 + seg * 1024),
            16, 0, 0);
      }
    }
    __syncthreads();
#pragma unroll
    for (int s = 0; s < 2; s++) {
      const unsigned short* Asb = (const unsigned short*)(smem + s * 8192);
      const unsigned short* Bsb = (const unsigned short*)(smem + 16384 + s * 8192);
      bf16x8 af[4], bfr[4];
#pragma unroll
      for (int i = 0; i < 4; i++) {
        af[i]  = *(const bf16x8*)(&Asb[(m0 + i * 16 + col) * 32 + quad * 8]);
        bfr[i] = *(const bf16x8*)(&Bsb[(n0 + i * 16 + col) * 32 + quad * 8]);
      }
#pragma unroll
      for (int i = 0; i < 4; i++)
#pragma unroll
        for (int j = 0; j < 4; j++)
          acc[i][j] = __builtin_amdgcn_mfma_f32_16x16x32_bf16(af[i], bfr[j], acc[i][j], 0, 0, 0);
    }
    __syncthreads();
  }

  // ---- epilogue: stage 32rows x 128cols slabs through LDS, packed stores ---
  // C/D frag layout: col = lane&15, row = quad*4 + reg.
  float bcol[4];
#pragma unroll
  for (int j = 0; j < 4; j++) bcol[j] = bias[brow0 + n0 + j * 16 + col];

  const int wp   = wave >> 1;   // wave-pair: rows m-base = wp*64
  const int lrow = tid >> 3;    // readback row 0..31
  const int cch  = tid & 7;     // readback col-chunk (16 elems each)

  if (MODE != 2) {
    unsigned short* epi = (unsigned short*)smem;
    const int EST = 136;  // shorts; 272 B row stride (16B-aligned, bank-skewed)
#pragma unroll
    for (int i = 0; i < 4; i++) {
#pragma unroll
      for (int j = 0; j < 4; j++) {
#pragma unroll
        for (int rr = 0; rr < 4; rr++) {
          float vv = acc[i][j][rr] + bcol[j];
          if (MODE == 0) vv = (vv > 0.f) ? (vv + 1.f) : __expf(vv);  // elu+1
          epi[(wp * 16 + quad * 4 + rr) * EST + n0 + j * 16 + col] = f2bf(vv);
        }
      }
      __syncthreads();
      const long gr = arow0 + (long)(lrow >> 4) * 64 + i * 16 + (lrow & 15);
      const long gc = brow0 + cch * 16;
      const unsigned short* src = &epi[lrow * EST + cch * 16];
      uint4 a  = *(const uint4*)src;
      uint4 b2 = *(const uint4*)(src + 8);
      unsigned short* Cp = (unsigned short*)Cout + gr * Nn + gc;
      *(uint4*)Cp       = a;
      *(uint4*)(Cp + 8) = b2;
      __syncthreads();
    }
  } else {
    float* epi = (float*)smem;
    const int ESF = 132;  // floats; 528 B row stride (16B-aligned, bank-skewed)
#pragma unroll
    for (int i = 0; i < 4; i++) {
#pragma unroll
      for (int j = 0; j < 4; j++) {
#pragma unroll
        for (int rr = 0; rr < 4; rr++) {
          epi[(wp * 16 + quad * 4 + rr) * ESF + n0 + j * 16 + col] =
              acc[i][j][rr] + bcol[j];
        }
      }
      __syncthreads();
      const long gr = arow0 + (long)(lrow >> 4) * 64 + i * 16 + (lrow & 15);
      const long gc = brow0 + cch * 16;
      const float* src = &epi[lrow * ESF + cch * 16];
      float* Cp = (float*)Cout + gr * Nn + gc;
#pragma unroll
      for (int s = 0; s < 4; s++)
        *(float4*)(Cp + s * 4) = *(const float4*)(src + s * 4);
      __syncthreads();
    }
  }
}

// ---------------- kv partials: kv[d][e] = sum_l kf[l][d]*v[l][e] ------------
// grid (NHG, NCHUNK), block 256. Non-atomic partial outputs per chunk.
__global__ __launch_bounds__(256) void kv_partial_kernel(const unsigned short* __restrict__ kf,
                                                         const unsigned short* __restrict__ vp,
                                                         float* __restrict__ kvp,
                                                         float* __restrict__ ksp) {
  __shared__ float ks[32 * 64];
  __shared__ float vs[32 * 64];
  const int hg = blockIdx.x;
  const int chunk = blockIdx.y;
  const int n = hg >> 4, h = hg & 15;
  const int tid = threadIdx.x;
  const int td = tid >> 4, te = tid & 15;   // thread covers d=td*4..+3, e=te*4..+3
  const long hoff = (long)n * EMB + h * HDIM;
  const int l0 = chunk * LCHUNK;

  float acc[4][4];
#pragma unroll
  for (int i = 0; i < 4; i++)
#pragma unroll
    for (int j = 0; j < 4; j++) acc[i][j] = 0.f;
  float ksacc[4] = {0.f, 0.f, 0.f, 0.f};

  const int lrow = tid >> 3;         // 0..31
  const int dcol = (tid & 7) * 8;    // 0..56

  for (int ls = 0; ls < LCHUNK; ls += 32) {
    const long g = (long)(l0 + ls + lrow) * (NBATCH * EMB) + hoff + dcol;
    uint4 kr = *(const uint4*)(kf + g);
    uint4 vr = *(const uint4*)(vp + g);
    float* kd = &ks[lrow * 64 + dcol];
    float* vd = &vs[lrow * 64 + dcol];
    uint32_t ku[4] = {kr.x, kr.y, kr.z, kr.w};
    uint32_t vu[4] = {vr.x, vr.y, vr.z, vr.w};
#pragma unroll
    for (int t2 = 0; t2 < 4; t2++) {
      kd[2 * t2]     = bf2f((unsigned short)(ku[t2] & 0xffffu));
      kd[2 * t2 + 1] = bf2f((unsigned short)(ku[t2] >> 16));
      vd[2 * t2]     = bf2f((unsigned short)(vu[t2] & 0xffffu));
      vd[2 * t2 + 1] = bf2f((unsigned short)(vu[t2] >> 16));
    }
    __syncthreads();
#pragma unroll
    for (int l = 0; l < 32; l++) {
      float kq[4], vq[4];
      *(float4*)kq = *(const float4*)(&ks[l * 64 + td * 4]);
      *(float4*)vq = *(const float4*)(&vs[l * 64 + te * 4]);
#pragma unroll
      for (int i = 0; i < 4; i++) {
        ksacc[i] += kq[i];
#pragma unroll
        for (int j = 0; j < 4; j++) acc[i][j] += kq[i] * vq[j];
      }
    }
    __syncthreads();
  }
  float* outp = kvp + ((long)chunk * NHG + hg) * 4096;
#pragma unroll
  for (int i = 0; i < 4; i++)
#pragma unroll
    for (int j = 0; j < 4; j++)
      outp[(td * 4 + i) * 64 + te * 4 + j] = acc[i][j];
  if (te == 0) {
    float* o2 = ksp + ((long)chunk * NHG + hg) * 64;
#pragma unroll
    for (int i = 0; i < 4; i++) o2[td * 4 + i] = ksacc[i];
  }
}

// ---------------- out1 = (qf @ kv) * 1/(qf.ksum + eps), bf16 row-major ------
// grid (NHG, 16), block 256. Each block: one head, 256 l-values (4 x 64).
__global__ __launch_bounds__(256) void attn_out_kernel(const unsigned short* __restrict__ qf,
                                                       const float* __restrict__ kvp,
                                                       const float* __restrict__ ksp,
                                                       unsigned short* __restrict__ out1) {
  __shared__ float kv_s[64 * 64];   // [d][e]
  __shared__ float ksum_s[64];
  __shared__ float qs[64 * 64];     // [d][l] transposed (bank-conflict-free reads)
  const int hg = blockIdx.x;
  const int lc = blockIdx.y;
  const int n = hg >> 4, h = hg & 15;
  const int tid = threadIdx.x;
  const int lane_l = tid & 63;   // l within sub-chunk
  const int eg = tid >> 6;       // wave -> e-group of 16
  const long hoff = (long)n * EMB + h * HDIM;

  // reduce kv partials into LDS
  for (int w = tid; w < 4096; w += 256) {
    float s = 0.f;
#pragma unroll
    for (int c = 0; c < NCHUNK; c++) s += kvp[((long)c * NHG + hg) * 4096 + w];
    kv_s[w] = s;
  }
  if (tid < 64) {
    float s = 0.f;
#pragma unroll
    for (int c = 0; c < NCHUNK; c++) s += ksp[((long)c * NHG + hg) * 64 + tid];
    ksum_s[tid] = s;
  }
  __syncthreads();

  const int sl = tid >> 2;           // staging l (0..63)
  const int sd0 = (tid & 3) * 16;    // staging d start

  for (int sc = 0; sc < 4; sc++) {
    const int lbase = lc * 256 + sc * 64;
    {
      const long g = (long)(lbase + sl) * (NBATCH * EMB) + hoff + sd0;
      uint4 a  = *(const uint4*)(qf + g);
      uint4 b2 = *(const uint4*)(qf + g + 8);
      uint32_t u[8] = {a.x, a.y, a.z, a.w, b2.x, b2.y, b2.z, b2.w};
#pragma unroll
      for (int t2 = 0; t2 < 8; t2++) {
        qs[(sd0 + 2 * t2) * 64 + sl]     = bf2f((unsigned short)(u[t2] & 0xffffu));
        qs[(sd0 + 2 * t2 + 1) * 64 + sl] = bf2f((unsigned short)(u[t2] >> 16));
      }
    }
    __syncthreads();

    float accv[16];
#pragma unroll
    for (int j = 0; j < 16; j++) accv[j] = 0.f;
    float denom = 0.f;
#pragma unroll 8
    for (int d = 0; d < 64; d++) {
      const float qd = qs[d * 64 + lane_l];
      denom += qd * ksum_s[d];
      const float* kvrow = &kv_s[d * 64 + eg * 16];
      float kvv[16];
      *(float4*)(kvv)      = *(const float4*)(kvrow);
      *(float4*)(kvv + 4)  = *(const float4*)(kvrow + 4);
      *(float4*)(kvv + 8)  = *(const float4*)(kvrow + 8);
      *(float4*)(kvv + 12) = *(const float4*)(kvrow + 12);
#pragma unroll
      for (int j = 0; j < 16; j++) accv[j] += qd * kvv[j];
    }
    const float z = 1.f / (denom + 1e-6f);
    const long ro = ((long)(lbase + lane_l) * NBATCH + n) * EMB + h * HDIM + eg * 16;
    uint32_t pk[8];
#pragma unroll
    for (int j = 0; j < 8; j++) {
      unsigned short lo = f2bf(accv[2 * j] * z);
      unsigned short hi = f2bf(accv[2 * j + 1] * z);
      pk[j] = (uint32_t)lo | ((uint32_t)hi << 16);
    }
    *(uint4*)(out1 + ro)     = make_uint4(pk[0], pk[1], pk[2], pk[3]);
    *(uint4*)(out1 + ro + 8) = make_uint4(pk[4], pk[5], pk[6], pk[7]);
    __syncthreads();
  }
}

// ---------------------------------------------------------------------------
extern "C" void kernel_launch(void* const* d_in, const int* in_sizes, int n_in,
                              void* d_out, int out_size, void* d_ws, size_t ws_size,
                              hipStream_t stream) {
  const float* q  = (const float*)d_in[0];
  const float* k  = (const float*)d_in[1];
  const float* v  = (const float*)d_in[2];
  const float* Wq = (const float*)d_in[3];
  const float* bq = (const float*)d_in[4];
  const float* Wk = (const float*)d_in[5];
  const float* bk = (const float*)d_in[6];
  const float* Wv = (const float*)d_in[7];
  const float* bv = (const float*)d_in[8];
  const float* Wo = (const float*)d_in[9];
  const float* bo = (const float*)d_in[10];

  char* ws = (char*)d_ws;
  const size_t BUF = (size_t)MROWS * EMB * 2;  // 33,554,432 B
  unsigned short* T0  = (unsigned short*)(ws);              // A-staging / out1
  unsigned short* qf  = (unsigned short*)(ws + BUF);
  unsigned short* kf  = (unsigned short*)(ws + 2 * BUF);
  unsigned short* vp  = (unsigned short*)(ws + 3 * BUF);
  unsigned short* Wqb = (unsigned short*)(ws + 4 * BUF);
  unsigned short* Wkb = Wqb + (size_t)EMB * EMB;
  unsigned short* Wvb = Wkb + (size_t)EMB * EMB;
  unsigned short* Wob = Wvb + (size_t)EMB * EMB;
  float* kvp = (float*)(ws + 4 * BUF + 4 * (size_t)EMB * EMB * 2);
  float* ksp = kvp + (size_t)NCHUNK * NHG * HDIM * HDIM;

  const int nQKV = MROWS * EMB;     // 16,777,216
  const int nW   = EMB * EMB;       // 1,048,576

  // all 4 weight matrices -> bf16 in one dispatch
  convert_w4<<<dim3(nW / 1024, 4), 256, 0, stream>>>(Wq, Wk, Wv, Wo,
                                                     Wqb, Wkb, Wvb, Wob, nW);

  dim3 gg(MROWS / 128, EMB / 128), bb(256);

  // projections (T0 reused as bf16 A-staging between GEMMs; stream-ordered)
  convert_kernel<<<nQKV / 1024, 256, 0, stream>>>(q, T0, nQKV);
  gemm_bt<0><<<gg, bb, 0, stream>>>(T0, Wqb, bq, qf, MROWS, EMB, EMB);
  convert_kernel<<<nQKV / 1024, 256, 0, stream>>>(k, T0, nQKV);
  gemm_bt<0><<<gg, bb, 0, stream>>>(T0, Wkb, bk, kf, MROWS, EMB, EMB);
  convert_kernel<<<nQKV / 1024, 256, 0, stream>>>(v, T0, nQKV);
  gemm_bt<1><<<gg, bb, 0, stream>>>(T0, Wvb, bv, vp, MROWS, EMB, EMB);

  // attention state + output (out1 -> T0)
  kv_partial_kernel<<<dim3(NHG, NCHUNK), 256, 0, stream>>>(kf, vp, kvp, ksp);
  attn_out_kernel<<<dim3(NHG, L_SEQ / 256), 256, 0, stream>>>(qf, kvp, ksp, T0);

  // final projection -> fp32 output
  gemm_bt<2><<<gg, bb, 0, stream>>>(T0, Wob, bo, d_out, MROWS, EMB, EMB);
}